// Round 1
// baseline (238.142 us; speedup 1.0000x reference)
//
#include <hip/hip_runtime.h>

// TTTConv: depthwise causal conv1d, B=4, N=4096, D=2048, K=4, fp32.
// out[b,n,d] = bias[d] + sum_{k=0..3} w[d,k] * x[b, n-3+k, d]  (x[t<0]=0)
// states[b,d,k] = x[b, N-4+k, d]   (fused into last-chunk blocks)
// Memory-bound: 128 MiB in + 128 MiB out -> ~42 us roofline at 6.3 TB/s.
//
// vs previous version:
//  - T=8 -> 16: halo read amplification 11/8 -> 19/16 (176 -> 152 MiB reads)
//  - states kernel fused into main (last-chunk blocks hold the data in regs)
//  - nontemporal output stores (output never re-read; keep halo rows in L2)
//  - bijective XCD swizzle (grid=2048, 2048%8==0) for halo L2 locality

constexpr int B = 4, N = 4096, D = 2048, K = 4;
constexpr int T = 16;             // timesteps per thread
constexpr int BLK = 256;          // threads per block
constexpr int DV = D / 4;         // 512 float4 lanes across channels
constexpr int DBLKS = DV / BLK;   // 2 d-blocks per row
constexpr int NCHUNKS = N / T;    // 256 n-chunks
constexpr int NWG = B * NCHUNKS * DBLKS;  // 2048 workgroups
constexpr int NXCD = 8;
constexpr int CPX = NWG / NXCD;   // 256 tiles per XCD

typedef float v4f __attribute__((ext_vector_type(4)));

__device__ inline void nt_store4(float* p, float4 v) {
    v4f t = {v.x, v.y, v.z, v.w};
    __builtin_nontemporal_store(t, (v4f*)p);
}

__global__ __launch_bounds__(BLK) void tttconv_main(
    const float* __restrict__ x, const float* __restrict__ w,
    const float* __restrict__ bias, float* __restrict__ out,
    float* __restrict__ st)
{
    // XCD-aware swizzle: hardware round-robins blockIdx across 8 XCDs;
    // give each XCD a contiguous chunk of logical tiles so the 3-row halo
    // shared by adjacent n-chunks hits the same per-XCD L2.
    int bid = blockIdx.x;
    int lid = (bid % NXCD) * CPX + (bid / NXCD);

    int b = lid / (NCHUNKS * DBLKS);
    int rem = lid % (NCHUNKS * DBLKS);
    int nchunk = rem / DBLKS;
    int dblk = rem % DBLKS;
    int dv = dblk * BLK + threadIdx.x;   // 0..511
    int d = dv * 4;
    int n0 = nchunk * T;

    // w is (D,K) row-major: w[d+c][k] -> 16 contiguous floats at d*K
    const float4* w4 = (const float4*)(w + (size_t)d * K);
    float4 wr0 = w4[0];  // w[d+0][0..3]
    float4 wr1 = w4[1];  // w[d+1][0..3]
    float4 wr2 = w4[2];
    float4 wr3 = w4[3];
    float4 bv = *(const float4*)(bias + d);

    const float* xbase = x + ((size_t)b * N) * D + d;
    float4 xin[T + K - 1];
    if (n0 >= K - 1) {
        // fast path: no boundary (all chunks except nchunk==0)
        #pragma unroll
        for (int j = 0; j < T + K - 1; ++j)
            xin[j] = *(const float4*)(xbase + (size_t)(n0 - (K - 1) + j) * D);
    } else {
        #pragma unroll
        for (int j = 0; j < T + K - 1; ++j) {
            int n = n0 - (K - 1) + j;
            xin[j] = (n >= 0) ? *(const float4*)(xbase + (size_t)n * D)
                              : make_float4(0.f, 0.f, 0.f, 0.f);
        }
    }

    float* obase = out + ((size_t)b * N) * D + d;
    #pragma unroll
    for (int t = 0; t < T; ++t) {
        float4 acc = bv;
        // channel c uses wr_c; input index n0+t-3+k -> xin[t+k]
        acc.x += wr0.x * xin[t + 0].x + wr0.y * xin[t + 1].x + wr0.z * xin[t + 2].x + wr0.w * xin[t + 3].x;
        acc.y += wr1.x * xin[t + 0].y + wr1.y * xin[t + 1].y + wr1.z * xin[t + 2].y + wr1.w * xin[t + 3].y;
        acc.z += wr2.x * xin[t + 0].z + wr2.y * xin[t + 1].z + wr2.z * xin[t + 2].z + wr2.w * xin[t + 3].z;
        acc.w += wr3.x * xin[t + 0].w + wr3.y * xin[t + 1].w + wr3.z * xin[t + 2].w + wr3.w * xin[t + 3].w;
        nt_store4(obase + (size_t)(n0 + t) * D, acc);
    }

    // Fused states write: the last n-chunk already holds x[b, N-4+k, d] in regs.
    // xin[j] <-> n = n0 - 3 + j; n = N-4+k  ->  j = T-1+k  (k = 0..3).
    if (nchunk == NCHUNKS - 1) {
        float* sbase = st + ((size_t)b * D + d) * K;  // st is (B, D, K) row-major
        float4 s0 = make_float4(xin[T - 1].x, xin[T].x, xin[T + 1].x, xin[T + 2].x);
        float4 s1 = make_float4(xin[T - 1].y, xin[T].y, xin[T + 1].y, xin[T + 2].y);
        float4 s2 = make_float4(xin[T - 1].z, xin[T].z, xin[T + 1].z, xin[T + 2].z);
        float4 s3 = make_float4(xin[T - 1].w, xin[T].w, xin[T + 1].w, xin[T + 2].w);
        *(float4*)(sbase + 0 * K) = s0;
        *(float4*)(sbase + 1 * K) = s1;
        *(float4*)(sbase + 2 * K) = s2;
        *(float4*)(sbase + 3 * K) = s3;
    }
}

extern "C" void kernel_launch(void* const* d_in, const int* in_sizes, int n_in,
                              void* d_out, int out_size, void* d_ws, size_t ws_size,
                              hipStream_t stream)
{
    const float* x    = (const float*)d_in[0];
    const float* w    = (const float*)d_in[1];
    const float* bias = (const float*)d_in[2];
    float* out = (float*)d_out;
    float* st  = out + (size_t)B * N * D;

    tttconv_main<<<NWG, BLK, 0, stream>>>(x, w, bias, out, st);
}

// Round 3
// 232.227 us; speedup vs baseline: 1.0255x; 1.0255x over previous
//
#include <hip/hip_runtime.h>

// TTTConv: depthwise causal conv1d, B=4, N=4096, D=2048, K=4, fp32.
// out[b,n,d] = bias[d] + sum_{k=0..3} w[d,k] * x[b, n-3+k, d]  (x[t<0]=0)
// states[b,d,k] = x[b, N-4+k, d]   (fused into last-chunk blocks)
// Memory-bound: 128 MiB in + 128 MiB out -> ~42 us roofline at 6.3 TB/s.
//
// Round-2 theory (resubmitted round 3 — round-2 bench died on container
// acquisition, not kernel): round-1 counters showed VGPR_Count=56 — the
// compiler's occupancy heuristic capped registers below the input-window
// size, forcing load serialization (per-wave MLP ~4 loads ->
// read-latency-bound at ~2.5 TB/s HBM while write-only fills hit 6.5).
// Fix: T=8 (11-row window, ~100 VGPR) + __launch_bounds__(256, 2) so the
// allocator may use up to 256 VGPR and keep all 11 window loads in flight
// back-to-back. Reverted round-1 extras (XCD swizzle, NT stores); kept
// fused states write.

constexpr int B = 4, N = 4096, D = 2048, K = 4;
constexpr int T = 8;              // timesteps per thread
constexpr int BLK = 256;          // threads per block
constexpr int DV = D / 4;         // 512 float4 lanes across channels
constexpr int DBLKS = DV / BLK;   // 2 d-blocks per row
constexpr int NCHUNKS = N / T;    // 512 n-chunks
constexpr int NWG = B * NCHUNKS * DBLKS;  // 4096 workgroups

__global__ __launch_bounds__(BLK, 2) void tttconv_main(
    const float* __restrict__ x, const float* __restrict__ w,
    const float* __restrict__ bias, float* __restrict__ out,
    float* __restrict__ st)
{
    int bid = blockIdx.x;
    int b = bid / (NCHUNKS * DBLKS);
    int rem = bid % (NCHUNKS * DBLKS);
    int nchunk = rem / DBLKS;
    int dblk = rem % DBLKS;
    int dv = dblk * BLK + threadIdx.x;   // 0..511
    int d = dv * 4;
    int n0 = nchunk * T;

    // w is (D,K) row-major: w[d+c][k] -> 16 contiguous floats at d*K
    const float4* w4 = (const float4*)(w + (size_t)d * K);
    float4 wr0 = w4[0];  // w[d+0][0..3]
    float4 wr1 = w4[1];  // w[d+1][0..3]
    float4 wr2 = w4[2];
    float4 wr3 = w4[3];
    float4 bv = *(const float4*)(bias + d);

    const float* xbase = x + ((size_t)b * N) * D + d;
    float4 xin[T + K - 1];
    if (n0 >= K - 1) {
        // fast path: no boundary — 11 independent loads, all issued upfront
        #pragma unroll
        for (int j = 0; j < T + K - 1; ++j)
            xin[j] = *(const float4*)(xbase + (size_t)(n0 - (K - 1) + j) * D);
    } else {
        #pragma unroll
        for (int j = 0; j < T + K - 1; ++j) {
            int n = n0 - (K - 1) + j;
            xin[j] = (n >= 0) ? *(const float4*)(xbase + (size_t)n * D)
                              : make_float4(0.f, 0.f, 0.f, 0.f);
        }
    }

    float* obase = out + ((size_t)b * N) * D + d;
    #pragma unroll
    for (int t = 0; t < T; ++t) {
        float4 acc = bv;
        // channel c uses wr_c; input index n0+t-3+k -> xin[t+k]
        acc.x += wr0.x * xin[t + 0].x + wr0.y * xin[t + 1].x + wr0.z * xin[t + 2].x + wr0.w * xin[t + 3].x;
        acc.y += wr1.x * xin[t + 0].y + wr1.y * xin[t + 1].y + wr1.z * xin[t + 2].y + wr1.w * xin[t + 3].y;
        acc.z += wr2.x * xin[t + 0].z + wr2.y * xin[t + 1].z + wr2.z * xin[t + 2].z + wr2.w * xin[t + 3].z;
        acc.w += wr3.x * xin[t + 0].w + wr3.y * xin[t + 1].w + wr3.z * xin[t + 2].w + wr3.w * xin[t + 3].w;
        *(float4*)(obase + (size_t)(n0 + t) * D) = acc;
    }

    // Fused states write: the last n-chunk already holds x[b, N-4+k, d] in regs.
    // xin[j] <-> n = n0 - 3 + j; n = N-4+k  ->  j = T-1+k  (k = 0..3).
    if (nchunk == NCHUNKS - 1) {
        float* sbase = st + ((size_t)b * D + d) * K;  // st is (B, D, K) row-major
        float4 s0 = make_float4(xin[T - 1].x, xin[T].x, xin[T + 1].x, xin[T + 2].x);
        float4 s1 = make_float4(xin[T - 1].y, xin[T].y, xin[T + 1].y, xin[T + 2].y);
        float4 s2 = make_float4(xin[T - 1].z, xin[T].z, xin[T + 1].z, xin[T + 2].z);
        float4 s3 = make_float4(xin[T - 1].w, xin[T].w, xin[T + 1].w, xin[T + 2].w);
        *(float4*)(sbase + 0 * K) = s0;
        *(float4*)(sbase + 1 * K) = s1;
        *(float4*)(sbase + 2 * K) = s2;
        *(float4*)(sbase + 3 * K) = s3;
    }
}

extern "C" void kernel_launch(void* const* d_in, const int* in_sizes, int n_in,
                              void* d_out, int out_size, void* d_ws, size_t ws_size,
                              hipStream_t stream)
{
    const float* x    = (const float*)d_in[0];
    const float* w    = (const float*)d_in[1];
    const float* bias = (const float*)d_in[2];
    float* out = (float*)d_out;
    float* st  = out + (size_t)B * N * D;

    tttconv_main<<<NWG, BLK, 0, stream>>>(x, w, bias, out, st);
}